// Round 6
// baseline (66.964 us; speedup 1.0000x reference)
//
#include <hip/hip_runtime.h>
#include <math.h>

// Problem: P=2, S=2, C=64, F=64, B=64
//   scores[p,s,c,d] = sum_{f,f2} dbfc[p,s,c,f,d,f2]      (268 MB streaming reduction)
//   weights = softmax(scores, axis=d)                     (fused into kernel B prologue)
//   v[b,ps,c,f1] = sum_f0 X[b,ps,c,f0] * wV[f1,f0]
//   out[c, b, ps*64+f1] = sum_d weights[ps,c,d] * v[b,ps,d,f1]

// clang native vector type — __builtin_nontemporal_load requires this
// (HIP_vector_type float4 is a struct and is rejected).
typedef float floatx4 __attribute__((ext_vector_type(4)));

// ---------------------------------------------------------------------------
// Kernel A: 2048 blocks x 256 threads (8 blocks/CU, 32 waves/CU — round-4
// occupancy held). NEW: each wave owns a dense contiguous 32 KB sub-range
// (vs round-4's 1KB-used-per-4KB interleave), swept as two dense half-streams
// (paired loads k and k+16 share an accumulator since 4*16 ≡ 0 mod 64).
// d-mapping within a wave: float4 idx w*2048 + k*64 + l  ->  d = 4k + (l>>4).
// 16 static accumulators (fully unrolled — rule #20), 16-lane butterfly,
// select-tree, LDS combine of the 4 waves, one partials store per block.
// ---------------------------------------------------------------------------
__global__ __launch_bounds__(256, 8) void scores_partial_kernel(
    const float* __restrict__ dbfc, float* __restrict__ partials)
{
    const int bid   = blockIdx.x;         // 0..2047
    const int slab  = bid >> 3;           // (ps*64 + c)
    const int chunk = bid & 7;
    const int t     = threadIdx.x;        // 0..255
    const int w     = t >> 6;             // wave 0..3
    const int l     = t & 63;             // lane 0..63
    const int g     = l >> 4;             // 0..3

    const floatx4* src = reinterpret_cast<const floatx4*>(dbfc)
                       + (size_t)bid * 8192 + w * 2048 + l;

    float acc[16];
#pragma unroll
    for (int k = 0; k < 16; ++k) acc[k] = 0.f;

#pragma unroll
    for (int k = 0; k < 16; ++k) {
        floatx4 a = __builtin_nontemporal_load(&src[k * 64]);
        floatx4 b = __builtin_nontemporal_load(&src[(k + 16) * 64]);
        acc[k] += ((a.x + a.y) + (a.z + a.w)) + ((b.x + b.y) + (b.z + b.w));
    }

    // butterfly-reduce each acc[k] across the 16 lanes sharing g = l>>4
#pragma unroll
    for (int k = 0; k < 16; ++k) {
#pragma unroll
        for (int m = 1; m < 16; m <<= 1)
            acc[k] += __shfl_xor(acc[k], m, 64);
    }
    // lane l holds the wave sum for d = 4*(l&15) + g in acc[l&15];
    // select with compile-time indices only (avoid scratch spill)
    float myv = 0.f;
#pragma unroll
    for (int k = 0; k < 16; ++k)
        if ((l & 15) == k) myv = acc[k];

    __shared__ float sm[4][64];
    sm[w][4 * (l & 15) + g] = myv;
    __syncthreads();

    if (t < 64) {
        float s = sm[0][t] + sm[1][t] + sm[2][t] + sm[3][t];
        partials[(size_t)chunk * 16384 + slab * 64 + t] = s;
    }
}

// ---------------------------------------------------------------------------
// Kernel B (identical to round 4): one block per (ps, b). Stages X-slab / wV
// in LDS, reduces the 8 score partials into Ws while staging, softmaxes the
// 64 rows (4 thr/row), computes v with 4x4 register tiles, transposes via
// LDS, then weights @ v. LDS rows stride 68 floats: conflict-free.
// ---------------------------------------------------------------------------
__global__ __launch_bounds__(256) void attn_out_kernel(
    const float* __restrict__ X, const float* __restrict__ wV,
    const float* __restrict__ partials, float* __restrict__ out)
{
    const int blk = blockIdx.x;   // 0..255
    const int ps  = blk >> 6;     // 0..3
    const int b   = blk & 63;     // 0..63
    const int t   = threadIdx.x;  // 0..255
    const int tc  = t >> 4;       // 0..15
    const int tf  = t & 15;       // 0..15

    __shared__ float Xs [64][68];   // X[b, ps, c, f0]
    __shared__ float wVs[64][68];   // wV[f1][f0]
    __shared__ float Ws [64][68];   // summed scores -> softmaxed weights [c][d]
    __shared__ float VsT[64][68];   // v transposed: [f1][c]

    const float4* xsrc = reinterpret_cast<const float4*>(X + (size_t)b * 16384 + ps * 4096);
    const float4* wsrc = reinterpret_cast<const float4*>(wV);
    const float4* psrc = reinterpret_cast<const float4*>(partials);
#pragma unroll
    for (int idx = t; idx < 1024; idx += 256) {
        int r = idx >> 4, jq = idx & 15, j = jq * 4;
        *reinterpret_cast<float4*>(&Xs [r][j]) = xsrc[idx];
        *reinterpret_cast<float4*>(&wVs[r][j]) = wsrc[idx];
        // sum the 8 chunk partials for (c=r, d=j..j+3)
        float4 s = make_float4(0.f, 0.f, 0.f, 0.f);
#pragma unroll
        for (int k = 0; k < 8; ++k) {
            float4 p = psrc[k * 4096 + (ps * 64 + r) * 16 + jq];
            s.x += p.x; s.y += p.y; s.z += p.z; s.w += p.w;
        }
        *reinterpret_cast<float4*>(&Ws [r][j]) = s;
    }
    __syncthreads();

    // v: acc[ci][fi] = sum_f0 Xs[4tc+ci][f0] * wVs[tf+16fi][f0]
    float acc[4][4] = {};
    for (int f0 = 0; f0 < 64; f0 += 4) {
        float4 xa[4], wv[4];
#pragma unroll
        for (int ci = 0; ci < 4; ++ci)
            xa[ci] = *reinterpret_cast<const float4*>(&Xs[4 * tc + ci][f0]);
#pragma unroll
        for (int fi = 0; fi < 4; ++fi)
            wv[fi] = *reinterpret_cast<const float4*>(&wVs[tf + 16 * fi][f0]);
#pragma unroll
        for (int ci = 0; ci < 4; ++ci)
#pragma unroll
            for (int fi = 0; fi < 4; ++fi)
                acc[ci][fi] += xa[ci].x * wv[fi].x + xa[ci].y * wv[fi].y
                             + xa[ci].z * wv[fi].z + xa[ci].w * wv[fi].w;
    }

    // softmax over d for each of the 64 rows of Ws; 4 threads per row
    {
        const int row = t >> 2, q = (t & 3) * 16;
        float e[16];
        float mx = -INFINITY;
#pragma unroll
        for (int i = 0; i < 16; ++i) mx = fmaxf(mx, Ws[row][q + i]);
        mx = fmaxf(mx, __shfl_xor(mx, 1, 64));
        mx = fmaxf(mx, __shfl_xor(mx, 2, 64));
        float sum = 0.f;
#pragma unroll
        for (int i = 0; i < 16; ++i) { e[i] = expf(Ws[row][q + i] - mx); sum += e[i]; }
        sum += __shfl_xor(sum, 1, 64);
        sum += __shfl_xor(sum, 2, 64);
        const float rinv = 1.0f / sum;
#pragma unroll
        for (int i = 0; i < 16; ++i) Ws[row][q + i] = e[i] * rinv;
    }

    // v -> LDS transposed
#pragma unroll
    for (int ci = 0; ci < 4; ++ci)
#pragma unroll
        for (int fi = 0; fi < 4; ++fi)
            VsT[tf + 16 * fi][4 * tc + ci] = acc[ci][fi];
    __syncthreads();

    // out: o[ci][fi] = sum_d Ws[4tc+ci][d] * VsT[tf+16fi][d]
    float o[4][4] = {};
    for (int d = 0; d < 64; d += 4) {
        float4 wa[4], va[4];
#pragma unroll
        for (int ci = 0; ci < 4; ++ci)
            wa[ci] = *reinterpret_cast<const float4*>(&Ws[4 * tc + ci][d]);
#pragma unroll
        for (int fi = 0; fi < 4; ++fi)
            va[fi] = *reinterpret_cast<const float4*>(&VsT[tf + 16 * fi][d]);
#pragma unroll
        for (int ci = 0; ci < 4; ++ci)
#pragma unroll
            for (int fi = 0; fi < 4; ++fi)
                o[ci][fi] += wa[ci].x * va[fi].x + wa[ci].y * va[fi].y
                           + wa[ci].z * va[fi].z + wa[ci].w * va[fi].w;
    }

    // out[c, b, ps*64 + f1],  c = 4tc+ci,  f1 = tf+16fi
#pragma unroll
    for (int ci = 0; ci < 4; ++ci) {
        const int c = 4 * tc + ci;
        float* orow = out + ((size_t)c * 64 + b) * 256 + ps * 64;
#pragma unroll
        for (int fi = 0; fi < 4; ++fi)
            orow[tf + 16 * fi] = o[ci][fi];
    }
}

extern "C" void kernel_launch(void* const* d_in, const int* in_sizes, int n_in,
                              void* d_out, int out_size, void* d_ws, size_t ws_size,
                              hipStream_t stream)
{
    const float* X    = (const float*)d_in[0];  // [64, 16384]
    const float* dbfc = (const float*)d_in[1];  // [2,2,64,64,64,64]
    const float* wV   = (const float*)d_in[2];  // [64, 64]
    float* out        = (float*)d_out;          // [64, 64, 256]
    float* partials   = (float*)d_ws;           // [8][256][64] = 512 KB scratch

    scores_partial_kernel<<<2048, 256, 0, stream>>>(dbfc, partials);
    attn_out_kernel<<<256, 256, 0, stream>>>(X, wV, partials, out);
}

// Round 7
// 59.876 us; speedup vs baseline: 1.1184x; 1.1184x over previous
//
#include <hip/hip_runtime.h>
#include <math.h>

// Problem: P=2, S=2, C=64, F=64, B=64
//   scores[p,s,c,d] = sum_{f,f2} dbfc[p,s,c,f,d,f2]      (268 MB streaming reduction)
//   weights = softmax(scores, axis=d)                     (fused into kernel B prologue)
//   v[b,ps,d,f1] = sum_f0 X[b,ps,d,f0] * wV[f1,f0]
//   out[c, b, ps*64+f1] = sum_d weights[ps,c,d] * v[b,ps,d,f1]

// clang native vector type — __builtin_nontemporal_load requires this
// (HIP_vector_type float4 is a struct and is rejected).
typedef float floatx4 __attribute__((ext_vector_type(4)));

// ---------------------------------------------------------------------------
// Kernel A — byte-identical to round 4 (best measured: 5.8-5.9 TB/s).
// 2048 blocks x 256 threads. Block = 1/8 of a (p,s,c) slab (128 KB).
// Thread t at iter i reads local float4 j = i*256+t -> d = (t>>4) + 16*(i&3):
// 4 register accumulators. Nontemporal loads. 16-lane shfl reduce, plain
// stores of the chunk's 64 partial sums.
// ---------------------------------------------------------------------------
__global__ __launch_bounds__(256) void scores_partial_kernel(
    const float* __restrict__ dbfc, float* __restrict__ partials)
{
    const int bid   = blockIdx.x;         // 0..2047
    const int slab  = bid >> 3;           // (ps*64 + c)
    const int chunk = bid & 7;
    const int t     = threadIdx.x;        // 0..255

    const floatx4* src = reinterpret_cast<const floatx4*>(dbfc)
                       + (size_t)slab * 65536 + chunk * 8192 + t;

    floatx4 a0 = (floatx4)0.f, a1 = (floatx4)0.f, a2 = (floatx4)0.f, a3 = (floatx4)0.f;
#pragma unroll 2
    for (int i = 0; i < 32; i += 4) {
        floatx4 v0 = __builtin_nontemporal_load(&src[(i + 0) * 256]);
        floatx4 v1 = __builtin_nontemporal_load(&src[(i + 1) * 256]);
        floatx4 v2 = __builtin_nontemporal_load(&src[(i + 2) * 256]);
        floatx4 v3 = __builtin_nontemporal_load(&src[(i + 3) * 256]);
        a0 += v0;
        a1 += v1;
        a2 += v2;
        a3 += v3;
    }
    float s0 = (a0.x + a0.y) + (a0.z + a0.w);
    float s1 = (a1.x + a1.y) + (a1.z + a1.w);
    float s2 = (a2.x + a2.y) + (a2.z + a2.w);
    float s3 = (a3.x + a3.y) + (a3.z + a3.w);
#pragma unroll
    for (int m = 1; m < 16; m <<= 1) {
        s0 += __shfl_xor(s0, m, 64);
        s1 += __shfl_xor(s1, m, 64);
        s2 += __shfl_xor(s2, m, 64);
        s3 += __shfl_xor(s3, m, 64);
    }
    if ((t & 15) == 0) {
        float* dst = partials + (size_t)chunk * 16384 + slab * 64 + (t >> 4);
        dst[ 0] = s0;
        dst[16] = s1;
        dst[32] = s2;
        dst[48] = s3;
    }
}

// ---------------------------------------------------------------------------
// Kernel B — restructured for latency: 1024 blocks x 256 threads.
// blk = cq*256 + ps*64 + b: block computes the 16-row c-quarter cq of the
// output for (ps,b). The 4 blocks of one (ps,b) are 256 apart -> same XCD
// (blockIdx%8 round-robin) -> X slab L2-reuse. Phase-1 v (full 64x64) is
// recomputed per block (VALU slack is free); phase-2 is quartered.
// LDS: Xs/wVs [64][68] + Ws [16][68] = 38.3 KB -> 4 blocks/CU, 16 waves/CU.
// VsT aliases Xs (barrier-separated). Stride-68 rows: conflict-free.
// ---------------------------------------------------------------------------
__global__ __launch_bounds__(256) void attn_out_kernel(
    const float* __restrict__ X, const float* __restrict__ wV,
    const float* __restrict__ partials, float* __restrict__ out)
{
    const int blk = blockIdx.x;        // 0..1023
    const int cq  = blk >> 8;          // 0..3 c-quarter
    const int ps  = (blk >> 6) & 3;    // 0..3
    const int b   = blk & 63;          // 0..63
    const int t   = threadIdx.x;       // 0..255
    const int tc  = t >> 4;            // 0..15
    const int tf  = t & 15;            // 0..15

    __shared__ float Xs [64][68];      // X[b, ps, d, f0]; later aliased as VsT[f1][d]
    __shared__ float wVs[64][68];      // wV[f1][f0]
    __shared__ float Ws [16][68];      // summed scores -> softmaxed weights [c_local][d]

    const float4* xsrc = reinterpret_cast<const float4*>(X + (size_t)b * 16384 + ps * 4096);
    const float4* wsrc = reinterpret_cast<const float4*>(wV);
    const float4* psrc = reinterpret_cast<const float4*>(partials);
#pragma unroll
    for (int idx = t; idx < 1024; idx += 256) {
        int r = idx >> 4, j = (idx & 15) * 4;
        *reinterpret_cast<float4*>(&Xs [r][j]) = xsrc[idx];
        *reinterpret_cast<float4*>(&wVs[r][j]) = wsrc[idx];
    }
    // Ws staging: 16 rows x 16 float4 = 256 float4, one per thread;
    // sum the 8 chunk partials for (c = cq*16 + r, d = jq*4..+3)
    {
        int r = t >> 4, jq = t & 15;
        float4 s = make_float4(0.f, 0.f, 0.f, 0.f);
#pragma unroll
        for (int k = 0; k < 8; ++k) {
            float4 p = psrc[k * 4096 + (ps * 64 + cq * 16 + r) * 16 + jq];
            s.x += p.x; s.y += p.y; s.z += p.z; s.w += p.w;
        }
        *reinterpret_cast<float4*>(&Ws[r][jq * 4]) = s;
    }
    __syncthreads();

    // phase 1 — v: acc[ci][fi] = sum_f0 Xs[4tc+ci][f0] * wVs[tf+16fi][f0]
    float acc[4][4] = {};
    for (int f0 = 0; f0 < 64; f0 += 4) {
        float4 xa[4], wv[4];
#pragma unroll
        for (int ci = 0; ci < 4; ++ci)
            xa[ci] = *reinterpret_cast<const float4*>(&Xs[4 * tc + ci][f0]);
#pragma unroll
        for (int fi = 0; fi < 4; ++fi)
            wv[fi] = *reinterpret_cast<const float4*>(&wVs[tf + 16 * fi][f0]);
#pragma unroll
        for (int ci = 0; ci < 4; ++ci)
#pragma unroll
            for (int fi = 0; fi < 4; ++fi)
                acc[ci][fi] += xa[ci].x * wv[fi].x + xa[ci].y * wv[fi].y
                             + xa[ci].z * wv[fi].z + xa[ci].w * wv[fi].w;
    }

    // softmax over d for the 16 rows of Ws; 4 threads per row (t < 64)
    if (t < 64) {
        const int row = t >> 2, q = (t & 3) * 16;
        float e[16];
        float mx = -INFINITY;
#pragma unroll
        for (int i = 0; i < 16; ++i) mx = fmaxf(mx, Ws[row][q + i]);
        mx = fmaxf(mx, __shfl_xor(mx, 1, 64));
        mx = fmaxf(mx, __shfl_xor(mx, 2, 64));
        float sum = 0.f;
#pragma unroll
        for (int i = 0; i < 16; ++i) { e[i] = expf(Ws[row][q + i] - mx); sum += e[i]; }
        sum += __shfl_xor(sum, 1, 64);
        sum += __shfl_xor(sum, 2, 64);
        const float rinv = 1.0f / sum;
#pragma unroll
        for (int i = 0; i < 16; ++i) Ws[row][q + i] = e[i] * rinv;
    }
    __syncthreads();   // all Xs reads done -> safe to overwrite with VsT

    // v -> LDS transposed, aliased into Xs: VsT[f1][d]
    float (*VsT)[68] = Xs;
#pragma unroll
    for (int ci = 0; ci < 4; ++ci)
#pragma unroll
        for (int fi = 0; fi < 4; ++fi)
            VsT[tf + 16 * fi][4 * tc + ci] = acc[ci][fi];
    __syncthreads();

    // phase 2 — o[fi] = sum_d Ws[c_local][d] * VsT[tf+16fi][d], c_local = t>>4
    float o[4] = {};
    for (int d = 0; d < 64; d += 4) {
        float4 wa = *reinterpret_cast<const float4*>(&Ws[tc][d]);
        float4 va[4];
#pragma unroll
        for (int fi = 0; fi < 4; ++fi)
            va[fi] = *reinterpret_cast<const float4*>(&VsT[tf + 16 * fi][d]);
#pragma unroll
        for (int fi = 0; fi < 4; ++fi)
            o[fi] += wa.x * va[fi].x + wa.y * va[fi].y
                   + wa.z * va[fi].z + wa.w * va[fi].w;
    }

    // out[c, b, ps*64 + f1],  c = cq*16 + tc,  f1 = tf+16fi
    {
        const int c = cq * 16 + tc;
        float* orow = out + ((size_t)c * 64 + b) * 256 + ps * 64;
#pragma unroll
        for (int fi = 0; fi < 4; ++fi)
            orow[tf + 16 * fi] = o[fi];
    }
}

extern "C" void kernel_launch(void* const* d_in, const int* in_sizes, int n_in,
                              void* d_out, int out_size, void* d_ws, size_t ws_size,
                              hipStream_t stream)
{
    const float* X    = (const float*)d_in[0];  // [64, 16384]
    const float* dbfc = (const float*)d_in[1];  // [2,2,64,64,64,64]
    const float* wV   = (const float*)d_in[2];  // [64, 64]
    float* out        = (float*)d_out;          // [64, 64, 256]
    float* partials   = (float*)d_ws;           // [8][256][64] = 512 KB scratch

    scores_partial_kernel<<<2048, 256, 0, stream>>>(dbfc, partials);
    attn_out_kernel<<<1024, 256, 0, stream>>>(X, wV, partials, out);
}